// Round 6
// baseline (333.079 us; speedup 1.0000x reference)
//
#include <hip/hip_runtime.h>
#include <hip/hip_fp16.h>

#define SLOPE_ATT 0.2f
#define SLOPE_ACT 0.01f

#define NB_CSR 64      // blocks in counting-sort passes (also rows of cntmat)
#define CHUNK 16384    // LDS histogram counters per chunk (64 KB)

typedef _Float16 hf8 __attribute__((ext_vector_type(8)));
typedef float f32x4 __attribute__((ext_vector_type(4)));

// ---------------------------------------------------------------------------
// MFMA fp16 GEMM: h[M][128] = A[M][K] @ B[K][128], B pre-transposed fp16
// BT[128][K]. No LDS. One wave = 32 rows x 128 cols: acc[2 rowfrag][8 colfrag].
template<int K, int H, bool A_FP32>
__global__ __launch_bounds__(256)
void gemm_mfma_kernel(const void* __restrict__ Av, const _Float16* __restrict__ BT,
                      const float* __restrict__ att_s, const float* __restrict__ att_d,
                      _Float16* __restrict__ hout, float* __restrict__ a_src,
                      float* __restrict__ a_dst, int M)
{
  const int lane = threadIdx.x & 63;
  const int wid  = threadIdx.x >> 6;
  const int li   = lane & 15;
  const int lk   = lane >> 4;
  const int rowbase = blockIdx.x * 128 + wid * 32;

  const float*    Af = (const float*)Av;
  const _Float16* Ah = (const _Float16*)Av;

  f32x4 acc[2][8];
#pragma unroll
  for (int i = 0; i < 2; ++i)
#pragma unroll
    for (int j = 0; j < 8; ++j) acc[i][j] = (f32x4){0.f, 0.f, 0.f, 0.f};

  const int r0 = min(rowbase + li,      M - 1);
  const int r1 = min(rowbase + 16 + li, M - 1);

#pragma unroll
  for (int ks = 0; ks < K / 32; ++ks) {
    const int kb = ks * 32 + lk * 8;
    hf8 a0, a1;
    if constexpr (A_FP32) {
      const float* p0 = &Af[(size_t)r0 * K + kb];
      const float* p1 = &Af[(size_t)r1 * K + kb];
      float4 x0a = *(const float4*)p0, x0b = *(const float4*)(p0 + 4);
      float4 x1a = *(const float4*)p1, x1b = *(const float4*)(p1 + 4);
      a0[0]=(_Float16)x0a.x; a0[1]=(_Float16)x0a.y; a0[2]=(_Float16)x0a.z; a0[3]=(_Float16)x0a.w;
      a0[4]=(_Float16)x0b.x; a0[5]=(_Float16)x0b.y; a0[6]=(_Float16)x0b.z; a0[7]=(_Float16)x0b.w;
      a1[0]=(_Float16)x1a.x; a1[1]=(_Float16)x1a.y; a1[2]=(_Float16)x1a.z; a1[3]=(_Float16)x1a.w;
      a1[4]=(_Float16)x1b.x; a1[5]=(_Float16)x1b.y; a1[6]=(_Float16)x1b.z; a1[7]=(_Float16)x1b.w;
    } else {
      a0 = *(const hf8*)&Ah[(size_t)r0 * K + kb];
      a1 = *(const hf8*)&Ah[(size_t)r1 * K + kb];
    }
#pragma unroll
    for (int cf = 0; cf < 8; ++cf) {
      hf8 b = *(const hf8*)&BT[(size_t)(cf * 16 + li) * K + kb];
      acc[0][cf] = __builtin_amdgcn_mfma_f32_16x16x32_f16(a0, b, acc[0][cf], 0, 0, 0);
      acc[1][cf] = __builtin_amdgcn_mfma_f32_16x16x32_f16(a1, b, acc[1][cf], 0, 0, 0);
    }
  }

  // epilogue
  float sA[8], dA[8];
#pragma unroll
  for (int cf = 0; cf < 8; ++cf) {
    sA[cf] = att_s[cf * 16 + li];
    dA[cf] = att_d[cf * 16 + li];
  }

  const bool full = (rowbase + 32) <= M;
#pragma unroll
  for (int rf = 0; rf < 2; ++rf) {
    const int rb = rowbase + rf * 16 + lk * 4;
#pragma unroll
    for (int reg = 0; reg < 4; ++reg) {
      const int r = rb + reg;
      if (full || r < M) {
#pragma unroll
        for (int cf = 0; cf < 8; ++cf)
          hout[(size_t)r * 128 + cf * 16 + li] = (_Float16)acc[rf][cf][reg];
      }
    }
    if constexpr (H == 4) {
#pragma unroll
      for (int hh = 0; hh < 4; ++hh) {
#pragma unroll
        for (int reg = 0; reg < 4; ++reg) {
          float sp = acc[rf][2*hh][reg] * sA[2*hh] + acc[rf][2*hh+1][reg] * sA[2*hh+1];
          float dp = acc[rf][2*hh][reg] * dA[2*hh] + acc[rf][2*hh+1][reg] * dA[2*hh+1];
          sp += __shfl_xor(sp, 1); sp += __shfl_xor(sp, 2);
          sp += __shfl_xor(sp, 4); sp += __shfl_xor(sp, 8);
          dp += __shfl_xor(dp, 1); dp += __shfl_xor(dp, 2);
          dp += __shfl_xor(dp, 4); dp += __shfl_xor(dp, 8);
          const int r = rb + reg;
          if (li == 0 && r < M) {
            a_src[(size_t)r * 4 + hh] = sp;
            a_dst[(size_t)r * 4 + hh] = dp;
          }
        }
      }
    } else {
#pragma unroll
      for (int reg = 0; reg < 4; ++reg) {
        float sp = 0.f, dp = 0.f;
#pragma unroll
        for (int cf = 0; cf < 8; ++cf) {
          sp += acc[rf][cf][reg] * sA[cf];
          dp += acc[rf][cf][reg] * dA[cf];
        }
        sp += __shfl_xor(sp, 1); sp += __shfl_xor(sp, 2);
        sp += __shfl_xor(sp, 4); sp += __shfl_xor(sp, 8);
        dp += __shfl_xor(dp, 1); dp += __shfl_xor(dp, 2);
        dp += __shfl_xor(dp, 4); dp += __shfl_xor(dp, 8);
        const int r = rb + reg;
        if (li == 0 && r < M) { a_src[r] = sp; a_dst[r] = dp; }
      }
    }
  }
}

// W [K][128] fp32 -> WT [128][K] fp16 (tiny)
__global__ __launch_bounds__(256)
void convW_kernel(const float* __restrict__ W, _Float16* __restrict__ WT, int K)
{
  int idx = blockIdx.x * 256 + threadIdx.x;
  if (idx >= K * 128) return;
  int k = idx >> 7, c = idx & 127;
  WT[(size_t)c * K + k] = (_Float16)W[idx];
}

// ---------------------------------------------------------------------------
// CSR build via privatized counting sort — NO global atomics.
// Pass 1: per-block LDS histogram (chunked over dst range) -> cntmat[b][d].
__global__ __launch_bounds__(256)
void count_kernel(const int* __restrict__ ei, int E, int N,
                  unsigned* __restrict__ cntmat)
{
  __shared__ unsigned cnt[CHUNK];
  const int b = blockIdx.x;
  const int EE = E + N;
  const int epb = (EE + NB_CSR - 1) / NB_CSR;
  const int lo = b * epb, hi = min(lo + epb, EE);
  for (int c0 = 0; c0 < N; c0 += CHUNK) {
    const int clen = min(CHUNK, N - c0);
    for (int j = threadIdx.x; j < clen; j += 256) cnt[j] = 0;
    __syncthreads();
    for (int i = lo + threadIdx.x; i < hi; i += 256) {
      int d = (i < E) ? ei[E + i] : (i - E);
      int r = d - c0;
      if (r >= 0 && r < clen) atomicAdd(&cnt[r], 1u);
    }
    __syncthreads();
    for (int j = threadIdx.x; j < clen; j += 256)
      cntmat[(size_t)b * N + c0 + j] = cnt[j];
    __syncthreads();
  }
}

// Pass 2: exclusive scan across blocks per dst (in-place) -> deg[d].
__global__ __launch_bounds__(256)
void colscan_kernel(unsigned* __restrict__ cntmat, unsigned* __restrict__ deg, int N)
{
  const int d = blockIdx.x * 256 + threadIdx.x;
  if (d >= N) return;
  unsigned off = 0;
#pragma unroll 8
  for (int b = 0; b < NB_CSR; ++b) {
    unsigned t = cntmat[(size_t)b * N + d];
    cntmat[(size_t)b * N + d] = off;
    off += t;
  }
  deg[d] = off;
}

__global__ __launch_bounds__(256)
void partial_sum_kernel(const unsigned* __restrict__ deg, unsigned* __restrict__ bsum,
                        int N, int C)
{
  __shared__ unsigned red[256];
  const int b = blockIdx.x;
  const int lo = b * C;
  const int hi = min(lo + C, N);
  unsigned s = 0;
  for (int i = lo + threadIdx.x; i < hi; i += 256) s += deg[i];
  red[threadIdx.x] = s;
  __syncthreads();
  for (int off = 128; off; off >>= 1) {
    if (threadIdx.x < off) red[threadIdx.x] += red[threadIdx.x + off];
    __syncthreads();
  }
  if (threadIdx.x == 0) bsum[b] = red[0];
}

__global__ __launch_bounds__(256)
void scan_bsum_kernel(const unsigned* __restrict__ bsum, unsigned* __restrict__ boff)
{
  __shared__ unsigned s[256];
  const int t = threadIdx.x;
  s[t] = bsum[t];
  __syncthreads();
  for (int off = 1; off < 256; off <<= 1) {
    unsigned v = (t >= off) ? s[t - off] : 0u;
    __syncthreads();
    s[t] += v;
    __syncthreads();
  }
  boff[t] = s[t] - bsum[t];   // exclusive
}

// C <= 256 assumed (N <= 65536).
__global__ __launch_bounds__(256)
void rowstart_kernel(const unsigned* __restrict__ deg, const unsigned* __restrict__ boff,
                     unsigned* __restrict__ row_start, int N, int C)
{
  __shared__ unsigned s[256];
  const int b = blockIdx.x;
  const int t = threadIdx.x;
  const int i = b * C + t;
  const unsigned d = (t < C && i < N) ? deg[i] : 0u;
  s[t] = d;
  __syncthreads();
  for (int off = 1; off < 256; off <<= 1) {
    unsigned v = (t >= off) ? s[t - off] : 0u;
    __syncthreads();
    s[t] += v;
    __syncthreads();
  }
  if (t < C && i < N) row_start[i] = boff[b] + s[t] - d;
}

// Pass 3: scatter with LDS-derived intra-block rank; plain stores only.
__global__ __launch_bounds__(256)
void scatter2_kernel(const int* __restrict__ ei, int E, int N,
                     const unsigned* __restrict__ cntmat,
                     const unsigned* __restrict__ row_start,
                     unsigned* __restrict__ csr_src)
{
  __shared__ unsigned cnt[CHUNK];
  const int b = blockIdx.x;
  const int EE = E + N;
  const int epb = (EE + NB_CSR - 1) / NB_CSR;
  const int lo = b * epb, hi = min(lo + epb, EE);
  for (int c0 = 0; c0 < N; c0 += CHUNK) {
    const int clen = min(CHUNK, N - c0);
    for (int j = threadIdx.x; j < clen; j += 256) cnt[j] = 0;
    __syncthreads();
    for (int i = lo + threadIdx.x; i < hi; i += 256) {
      int s, d;
      if (i < E) { s = ei[i]; d = ei[E + i]; } else { s = d = i - E; }
      int r = d - c0;
      if (r >= 0 && r < clen) {
        unsigned rank = atomicAdd(&cnt[r], 1u);
        unsigned pos = row_start[d] + cntmat[(size_t)b * N + d] + rank;
        csr_src[pos] = (unsigned)s;
      }
    }
    __syncthreads();
  }
}

// ---------------------------------------------------------------------------
// Fused per-node aggregation (unchanged from R5).
template<int H, bool OUT_HALF>
__global__ __launch_bounds__(256)
void aggregate_kernel(const unsigned* __restrict__ row_start,
                      const unsigned* __restrict__ deg,
                      const unsigned* __restrict__ csr_src,
                      const __half* __restrict__ h,
                      const float* __restrict__ a_src,
                      const float* __restrict__ a_dst,
                      const float* __restrict__ bias,
                      void* __restrict__ outv, int N)
{
  const int n = blockIdx.x * 4 + (threadIdx.x >> 6);
  if (n >= N) return;
  const int l = threadIdx.x & 63;
  const int hd = (H == 4) ? (l >> 4) : 0;

  const float adn = a_dst[(size_t)n * H + hd];
  const unsigned beg = row_start[n];
  const unsigned cnt = deg[n];              // >= 1 (self loop)
  const __half2* __restrict__ h2 = (const __half2*)h;

  float Z = 0.f, ax = 0.f, ay = 0.f;
  unsigned i = 0;
  for (; i + 4 <= cnt; i += 4) {
    unsigned s0 = csr_src[beg + i];
    unsigned s1 = csr_src[beg + i + 1];
    unsigned s2 = csr_src[beg + i + 2];
    unsigned s3 = csr_src[beg + i + 3];
    float e0 = a_src[(size_t)s0 * H + hd] + adn;
    float e1 = a_src[(size_t)s1 * H + hd] + adn;
    float e2 = a_src[(size_t)s2 * H + hd] + adn;
    float e3 = a_src[(size_t)s3 * H + hd] + adn;
    float2 v0 = __half22float2(h2[(size_t)s0 * 64 + l]);
    float2 v1 = __half22float2(h2[(size_t)s1 * 64 + l]);
    float2 v2 = __half22float2(h2[(size_t)s2 * 64 + l]);
    float2 v3 = __half22float2(h2[(size_t)s3 * 64 + l]);
    e0 = (e0 >= 0.f) ? e0 : SLOPE_ATT * e0;
    e1 = (e1 >= 0.f) ? e1 : SLOPE_ATT * e1;
    e2 = (e2 >= 0.f) ? e2 : SLOPE_ATT * e2;
    e3 = (e3 >= 0.f) ? e3 : SLOPE_ATT * e3;
    float w0 = __expf(e0), w1 = __expf(e1), w2 = __expf(e2), w3 = __expf(e3);
    Z  += (w0 + w1) + (w2 + w3);
    ax += w0 * v0.x + w1 * v1.x + w2 * v2.x + w3 * v3.x;
    ay += w0 * v0.y + w1 * v1.y + w2 * v2.y + w3 * v3.y;
  }
  for (; i < cnt; ++i) {
    unsigned s0 = csr_src[beg + i];
    float e0 = a_src[(size_t)s0 * H + hd] + adn;
    e0 = (e0 >= 0.f) ? e0 : SLOPE_ATT * e0;
    float w0 = __expf(e0);
    float2 v0 = __half22float2(h2[(size_t)s0 * 64 + l]);
    Z  += w0;
    ax += w0 * v0.x;
    ay += w0 * v0.y;
  }
  const float inv = 1.f / (Z + 1e-16f);
  float2 b = ((const float2*)bias)[l];
  float ox = ax * inv + b.x;
  float oy = ay * inv + b.y;
  ox = (ox >= 0.f) ? ox : SLOPE_ACT * ox;
  oy = (oy >= 0.f) ? oy : SLOPE_ACT * oy;
  if constexpr (OUT_HALF)
    ((__half2*)outv)[(size_t)n * 64 + l] = __floats2half2_rn(ox, oy);
  else
    ((float2*)outv)[(size_t)n * 64 + l] = make_float2(ox, oy);
}

// ---------------------------------------------------------------------------
extern "C" void kernel_launch(void* const* d_in, const int* in_sizes, int n_in,
                              void* d_out, int out_size, void* d_ws, size_t ws_size,
                              hipStream_t stream)
{
  const float* x   = (const float*)d_in[0];
  const int*   ei  = (const int*)d_in[1];
  const float* W1  = (const float*)d_in[2];
  const float* as1 = (const float*)d_in[3];
  const float* ad1 = (const float*)d_in[4];
  const float* b1  = (const float*)d_in[5];
  const float* W2  = (const float*)d_in[6];
  const float* as2 = (const float*)d_in[7];
  const float* ad2 = (const float*)d_in[8];
  const float* b2  = (const float*)d_in[9];
  float* out = (float*)d_out;

  const int N  = in_sizes[0] / 256;
  const int E  = in_sizes[1] / 2;
  const int EE = E + N;
  const int C  = (N + 255) / 256;   // <= 256 for N <= 65536

  float* ws = (float*)d_ws;
  size_t o = 0;
  _Float16* h    = (_Float16*)(ws + o); o += (size_t)N * 64;   // [N][128] fp16
  _Float16* act1 = (_Float16*)(ws + o); o += (size_t)N * 64;   // [N][128] fp16
  float* asv = ws + o; o += (size_t)N * 4;
  float* adv = ws + o; o += (size_t)N * 4;
  _Float16* W1T = (_Float16*)(ws + o); o += 128 * 256 / 2;     // [128][256] fp16
  _Float16* W2T = (_Float16*)(ws + o); o += 128 * 128 / 2;     // [128][128] fp16
  unsigned* deg       = (unsigned*)(ws + o); o += (size_t)N;
  unsigned* row_start = (unsigned*)(ws + o); o += (size_t)N;
  unsigned* bsum      = (unsigned*)(ws + o); o += 256;
  unsigned* boff      = (unsigned*)(ws + o); o += 256;
  unsigned* csr_src   = (unsigned*)(ws + o); o += (size_t)EE;
  unsigned* cntmat    = (unsigned*)(ws + o); o += (size_t)NB_CSR * N;  // 12.8 MB

  const int ngrid = (N + 3) / 4;
  const int ggrid = (N + 127) / 128;

  // ---- weight transpose+fp16 (tiny) ----
  convW_kernel<<<(256 * 128 + 255) / 256, 256, 0, stream>>>(W1, W1T, 256);
  convW_kernel<<<(128 * 128 + 255) / 256, 256, 0, stream>>>(W2, W2T, 128);

  // ---- CSR build (no global atomics) ----
  count_kernel<<<NB_CSR, 256, 0, stream>>>(ei, E, N, cntmat);
  colscan_kernel<<<(N + 255) / 256, 256, 0, stream>>>(cntmat, deg, N);
  partial_sum_kernel<<<256, 256, 0, stream>>>(deg, bsum, N, C);
  scan_bsum_kernel<<<1, 256, 0, stream>>>(bsum, boff);
  rowstart_kernel<<<256, 256, 0, stream>>>(deg, boff, row_start, N, C);
  scatter2_kernel<<<NB_CSR, 256, 0, stream>>>(ei, E, N, cntmat, row_start, csr_src);

  // ---- layer 1 (K=256, H=4): A = x fp32 ----
  gemm_mfma_kernel<256, 4, true><<<ggrid, 256, 0, stream>>>(
      x, W1T, as1, ad1, h, asv, adv, N);
  aggregate_kernel<4, true><<<ngrid, 256, 0, stream>>>(
      row_start, deg, csr_src, (const __half*)h, asv, adv, b1, act1, N);

  // ---- layer 2 (K=128, H=1): A = act1 fp16 ----
  gemm_mfma_kernel<128, 1, false><<<ggrid, 256, 0, stream>>>(
      act1, W2T, as2, ad2, h, asv, adv, N);
  aggregate_kernel<1, false><<<ngrid, 256, 0, stream>>>(
      row_start, deg, csr_src, (const __half*)h, asv, adv, b2, out, N);
}

// Round 7
// 231.560 us; speedup vs baseline: 1.4384x; 1.4384x over previous
//
#include <hip/hip_runtime.h>
#include <hip/hip_fp16.h>

#define SLOPE_ATT 0.2f
#define SLOPE_ACT 0.01f

#define NB_CSR 64      // edge-range blocks in counting-sort passes
#define CHUNK 16384    // LDS histogram counters per chunk (64 KB)

typedef _Float16 hf8 __attribute__((ext_vector_type(8)));
typedef float f32x4 __attribute__((ext_vector_type(4)));

// ---------------------------------------------------------------------------
// MFMA fp16 GEMM: h[M][128] = A[M][K] @ B[K][128], B pre-transposed fp16
// BT[128][K]. No LDS. One wave = 32 rows x 128 cols: acc[2 rowfrag][8 colfrag].
template<int K, int H, bool A_FP32>
__global__ __launch_bounds__(256)
void gemm_mfma_kernel(const void* __restrict__ Av, const _Float16* __restrict__ BT,
                      const float* __restrict__ att_s, const float* __restrict__ att_d,
                      _Float16* __restrict__ hout, float* __restrict__ a_src,
                      float* __restrict__ a_dst, int M)
{
  const int lane = threadIdx.x & 63;
  const int wid  = threadIdx.x >> 6;
  const int li   = lane & 15;
  const int lk   = lane >> 4;
  const int rowbase = blockIdx.x * 128 + wid * 32;

  const float*    Af = (const float*)Av;
  const _Float16* Ah = (const _Float16*)Av;

  f32x4 acc[2][8];
#pragma unroll
  for (int i = 0; i < 2; ++i)
#pragma unroll
    for (int j = 0; j < 8; ++j) acc[i][j] = (f32x4){0.f, 0.f, 0.f, 0.f};

  const int r0 = min(rowbase + li,      M - 1);
  const int r1 = min(rowbase + 16 + li, M - 1);

#pragma unroll
  for (int ks = 0; ks < K / 32; ++ks) {
    const int kb = ks * 32 + lk * 8;
    hf8 a0, a1;
    if constexpr (A_FP32) {
      const float* p0 = &Af[(size_t)r0 * K + kb];
      const float* p1 = &Af[(size_t)r1 * K + kb];
      float4 x0a = *(const float4*)p0, x0b = *(const float4*)(p0 + 4);
      float4 x1a = *(const float4*)p1, x1b = *(const float4*)(p1 + 4);
      a0[0]=(_Float16)x0a.x; a0[1]=(_Float16)x0a.y; a0[2]=(_Float16)x0a.z; a0[3]=(_Float16)x0a.w;
      a0[4]=(_Float16)x0b.x; a0[5]=(_Float16)x0b.y; a0[6]=(_Float16)x0b.z; a0[7]=(_Float16)x0b.w;
      a1[0]=(_Float16)x1a.x; a1[1]=(_Float16)x1a.y; a1[2]=(_Float16)x1a.z; a1[3]=(_Float16)x1a.w;
      a1[4]=(_Float16)x1b.x; a1[5]=(_Float16)x1b.y; a1[6]=(_Float16)x1b.z; a1[7]=(_Float16)x1b.w;
    } else {
      a0 = *(const hf8*)&Ah[(size_t)r0 * K + kb];
      a1 = *(const hf8*)&Ah[(size_t)r1 * K + kb];
    }
#pragma unroll
    for (int cf = 0; cf < 8; ++cf) {
      hf8 b = *(const hf8*)&BT[(size_t)(cf * 16 + li) * K + kb];
      acc[0][cf] = __builtin_amdgcn_mfma_f32_16x16x32_f16(a0, b, acc[0][cf], 0, 0, 0);
      acc[1][cf] = __builtin_amdgcn_mfma_f32_16x16x32_f16(a1, b, acc[1][cf], 0, 0, 0);
    }
  }

  // epilogue
  float sA[8], dA[8];
#pragma unroll
  for (int cf = 0; cf < 8; ++cf) {
    sA[cf] = att_s[cf * 16 + li];
    dA[cf] = att_d[cf * 16 + li];
  }

  const bool full = (rowbase + 32) <= M;
#pragma unroll
  for (int rf = 0; rf < 2; ++rf) {
    const int rb = rowbase + rf * 16 + lk * 4;
#pragma unroll
    for (int reg = 0; reg < 4; ++reg) {
      const int r = rb + reg;
      if (full || r < M) {
#pragma unroll
        for (int cf = 0; cf < 8; ++cf)
          hout[(size_t)r * 128 + cf * 16 + li] = (_Float16)acc[rf][cf][reg];
      }
    }
    if constexpr (H == 4) {
#pragma unroll
      for (int hh = 0; hh < 4; ++hh) {
#pragma unroll
        for (int reg = 0; reg < 4; ++reg) {
          float sp = acc[rf][2*hh][reg] * sA[2*hh] + acc[rf][2*hh+1][reg] * sA[2*hh+1];
          float dp = acc[rf][2*hh][reg] * dA[2*hh] + acc[rf][2*hh+1][reg] * dA[2*hh+1];
          sp += __shfl_xor(sp, 1); sp += __shfl_xor(sp, 2);
          sp += __shfl_xor(sp, 4); sp += __shfl_xor(sp, 8);
          dp += __shfl_xor(dp, 1); dp += __shfl_xor(dp, 2);
          dp += __shfl_xor(dp, 4); dp += __shfl_xor(dp, 8);
          const int r = rb + reg;
          if (li == 0 && r < M) {
            a_src[(size_t)r * 4 + hh] = sp;
            a_dst[(size_t)r * 4 + hh] = dp;
          }
        }
      }
    } else {
#pragma unroll
      for (int reg = 0; reg < 4; ++reg) {
        float sp = 0.f, dp = 0.f;
#pragma unroll
        for (int cf = 0; cf < 8; ++cf) {
          sp += acc[rf][cf][reg] * sA[cf];
          dp += acc[rf][cf][reg] * dA[cf];
        }
        sp += __shfl_xor(sp, 1); sp += __shfl_xor(sp, 2);
        sp += __shfl_xor(sp, 4); sp += __shfl_xor(sp, 8);
        dp += __shfl_xor(dp, 1); dp += __shfl_xor(dp, 2);
        dp += __shfl_xor(dp, 4); dp += __shfl_xor(dp, 8);
        const int r = rb + reg;
        if (li == 0 && r < M) { a_src[r] = sp; a_dst[r] = dp; }
      }
    }
  }
}

// W [K][128] fp32 -> WT [128][K] fp16 (tiny)
__global__ __launch_bounds__(256)
void convW_kernel(const float* __restrict__ W, _Float16* __restrict__ WT, int K)
{
  int idx = blockIdx.x * 256 + threadIdx.x;
  if (idx >= K * 128) return;
  int k = idx >> 7, c = idx & 127;
  WT[(size_t)c * K + k] = (_Float16)W[idx];
}

// ---------------------------------------------------------------------------
// CSR build via privatized counting sort — NO global atomics.
// Grid (NB_CSR, nchunk): block (b,c) scans edge range b, histograms dsts in
// chunk c. One chunk pass per block -> full grid parallelism.
__global__ __launch_bounds__(256)
void count_kernel(const int* __restrict__ ei, int E, int N,
                  unsigned* __restrict__ cntmat)
{
  __shared__ unsigned cnt[CHUNK];
  const int b = blockIdx.x;
  const int c0 = blockIdx.y * CHUNK;
  const int clen = min(CHUNK, N - c0);
  const int EE = E + N;
  const int epb = (EE + NB_CSR - 1) / NB_CSR;
  const int lo = b * epb, hi = min(lo + epb, EE);

  for (int j = threadIdx.x; j < clen; j += 256) cnt[j] = 0;
  __syncthreads();
  for (int i = lo + threadIdx.x; i < hi; i += 256) {
    int d = (i < E) ? ei[E + i] : (i - E);
    int r = d - c0;
    if (r >= 0 && r < clen) atomicAdd(&cnt[r], 1u);
  }
  __syncthreads();
  for (int j = threadIdx.x; j < clen; j += 256)
    cntmat[(size_t)b * N + c0 + j] = cnt[j];
}

// Exclusive scan across blocks per dst (in-place) -> deg[d].
__global__ __launch_bounds__(256)
void colscan_kernel(unsigned* __restrict__ cntmat, unsigned* __restrict__ deg, int N)
{
  const int d = blockIdx.x * 256 + threadIdx.x;
  if (d >= N) return;
  unsigned off = 0;
#pragma unroll 8
  for (int b = 0; b < NB_CSR; ++b) {
    unsigned t = cntmat[(size_t)b * N + d];
    cntmat[(size_t)b * N + d] = off;
    off += t;
  }
  deg[d] = off;
}

__global__ __launch_bounds__(256)
void partial_sum_kernel(const unsigned* __restrict__ deg, unsigned* __restrict__ bsum,
                        int N, int C)
{
  __shared__ unsigned red[256];
  const int b = blockIdx.x;
  const int lo = b * C;
  const int hi = min(lo + C, N);
  unsigned s = 0;
  for (int i = lo + threadIdx.x; i < hi; i += 256) s += deg[i];
  red[threadIdx.x] = s;
  __syncthreads();
  for (int off = 128; off; off >>= 1) {
    if (threadIdx.x < off) red[threadIdx.x] += red[threadIdx.x + off];
    __syncthreads();
  }
  if (threadIdx.x == 0) bsum[b] = red[0];
}

__global__ __launch_bounds__(256)
void scan_bsum_kernel(const unsigned* __restrict__ bsum, unsigned* __restrict__ boff)
{
  __shared__ unsigned s[256];
  const int t = threadIdx.x;
  s[t] = bsum[t];
  __syncthreads();
  for (int off = 1; off < 256; off <<= 1) {
    unsigned v = (t >= off) ? s[t - off] : 0u;
    __syncthreads();
    s[t] += v;
    __syncthreads();
  }
  boff[t] = s[t] - bsum[t];   // exclusive
}

// C <= 256 assumed (N <= 65536).
__global__ __launch_bounds__(256)
void rowstart_kernel(const unsigned* __restrict__ deg, const unsigned* __restrict__ boff,
                     unsigned* __restrict__ row_start, int N, int C)
{
  __shared__ unsigned s[256];
  const int b = blockIdx.x;
  const int t = threadIdx.x;
  const int i = b * C + t;
  const unsigned d = (t < C && i < N) ? deg[i] : 0u;
  s[t] = d;
  __syncthreads();
  for (int off = 1; off < 256; off <<= 1) {
    unsigned v = (t >= off) ? s[t - off] : 0u;
    __syncthreads();
    s[t] += v;
    __syncthreads();
  }
  if (t < C && i < N) row_start[i] = boff[b] + s[t] - d;
}

// Scatter with LDS-derived intra-(range,chunk) rank; plain stores only.
__global__ __launch_bounds__(256)
void scatter2_kernel(const int* __restrict__ ei, int E, int N,
                     const unsigned* __restrict__ cntmat,
                     const unsigned* __restrict__ row_start,
                     unsigned* __restrict__ csr_src)
{
  __shared__ unsigned cnt[CHUNK];
  const int b = blockIdx.x;
  const int c0 = blockIdx.y * CHUNK;
  const int clen = min(CHUNK, N - c0);
  const int EE = E + N;
  const int epb = (EE + NB_CSR - 1) / NB_CSR;
  const int lo = b * epb, hi = min(lo + epb, EE);

  for (int j = threadIdx.x; j < clen; j += 256) cnt[j] = 0;
  __syncthreads();
  for (int i = lo + threadIdx.x; i < hi; i += 256) {
    int s, d;
    if (i < E) { s = ei[i]; d = ei[E + i]; } else { s = d = i - E; }
    int r = d - c0;
    if (r >= 0 && r < clen) {
      unsigned rank = atomicAdd(&cnt[r], 1u);
      unsigned pos = row_start[d] + cntmat[(size_t)b * N + d] + rank;
      csr_src[pos] = (unsigned)s;
    }
  }
}

// ---------------------------------------------------------------------------
// Fused per-node aggregation (unchanged from R5).
template<int H, bool OUT_HALF>
__global__ __launch_bounds__(256)
void aggregate_kernel(const unsigned* __restrict__ row_start,
                      const unsigned* __restrict__ deg,
                      const unsigned* __restrict__ csr_src,
                      const __half* __restrict__ h,
                      const float* __restrict__ a_src,
                      const float* __restrict__ a_dst,
                      const float* __restrict__ bias,
                      void* __restrict__ outv, int N)
{
  const int n = blockIdx.x * 4 + (threadIdx.x >> 6);
  if (n >= N) return;
  const int l = threadIdx.x & 63;
  const int hd = (H == 4) ? (l >> 4) : 0;

  const float adn = a_dst[(size_t)n * H + hd];
  const unsigned beg = row_start[n];
  const unsigned cnt = deg[n];              // >= 1 (self loop)
  const __half2* __restrict__ h2 = (const __half2*)h;

  float Z = 0.f, ax = 0.f, ay = 0.f;
  unsigned i = 0;
  for (; i + 4 <= cnt; i += 4) {
    unsigned s0 = csr_src[beg + i];
    unsigned s1 = csr_src[beg + i + 1];
    unsigned s2 = csr_src[beg + i + 2];
    unsigned s3 = csr_src[beg + i + 3];
    float e0 = a_src[(size_t)s0 * H + hd] + adn;
    float e1 = a_src[(size_t)s1 * H + hd] + adn;
    float e2 = a_src[(size_t)s2 * H + hd] + adn;
    float e3 = a_src[(size_t)s3 * H + hd] + adn;
    float2 v0 = __half22float2(h2[(size_t)s0 * 64 + l]);
    float2 v1 = __half22float2(h2[(size_t)s1 * 64 + l]);
    float2 v2 = __half22float2(h2[(size_t)s2 * 64 + l]);
    float2 v3 = __half22float2(h2[(size_t)s3 * 64 + l]);
    e0 = (e0 >= 0.f) ? e0 : SLOPE_ATT * e0;
    e1 = (e1 >= 0.f) ? e1 : SLOPE_ATT * e1;
    e2 = (e2 >= 0.f) ? e2 : SLOPE_ATT * e2;
    e3 = (e3 >= 0.f) ? e3 : SLOPE_ATT * e3;
    float w0 = __expf(e0), w1 = __expf(e1), w2 = __expf(e2), w3 = __expf(e3);
    Z  += (w0 + w1) + (w2 + w3);
    ax += w0 * v0.x + w1 * v1.x + w2 * v2.x + w3 * v3.x;
    ay += w0 * v0.y + w1 * v1.y + w2 * v2.y + w3 * v3.y;
  }
  for (; i < cnt; ++i) {
    unsigned s0 = csr_src[beg + i];
    float e0 = a_src[(size_t)s0 * H + hd] + adn;
    e0 = (e0 >= 0.f) ? e0 : SLOPE_ATT * e0;
    float w0 = __expf(e0);
    float2 v0 = __half22float2(h2[(size_t)s0 * 64 + l]);
    Z  += w0;
    ax += w0 * v0.x;
    ay += w0 * v0.y;
  }
  const float inv = 1.f / (Z + 1e-16f);
  float2 b = ((const float2*)bias)[l];
  float ox = ax * inv + b.x;
  float oy = ay * inv + b.y;
  ox = (ox >= 0.f) ? ox : SLOPE_ACT * ox;
  oy = (oy >= 0.f) ? oy : SLOPE_ACT * oy;
  if constexpr (OUT_HALF)
    ((__half2*)outv)[(size_t)n * 64 + l] = __floats2half2_rn(ox, oy);
  else
    ((float2*)outv)[(size_t)n * 64 + l] = make_float2(ox, oy);
}

// ---------------------------------------------------------------------------
extern "C" void kernel_launch(void* const* d_in, const int* in_sizes, int n_in,
                              void* d_out, int out_size, void* d_ws, size_t ws_size,
                              hipStream_t stream)
{
  const float* x   = (const float*)d_in[0];
  const int*   ei  = (const int*)d_in[1];
  const float* W1  = (const float*)d_in[2];
  const float* as1 = (const float*)d_in[3];
  const float* ad1 = (const float*)d_in[4];
  const float* b1  = (const float*)d_in[5];
  const float* W2  = (const float*)d_in[6];
  const float* as2 = (const float*)d_in[7];
  const float* ad2 = (const float*)d_in[8];
  const float* b2  = (const float*)d_in[9];
  float* out = (float*)d_out;

  const int N  = in_sizes[0] / 256;
  const int E  = in_sizes[1] / 2;
  const int EE = E + N;
  const int C  = (N + 255) / 256;           // <= 256 for N <= 65536
  const int NCH = (N + CHUNK - 1) / CHUNK;  // dst chunks

  float* ws = (float*)d_ws;
  size_t o = 0;
  _Float16* h    = (_Float16*)(ws + o); o += (size_t)N * 64;   // [N][128] fp16
  _Float16* act1 = (_Float16*)(ws + o); o += (size_t)N * 64;   // [N][128] fp16
  float* asv = ws + o; o += (size_t)N * 4;
  float* adv = ws + o; o += (size_t)N * 4;
  _Float16* W1T = (_Float16*)(ws + o); o += 128 * 256 / 2;     // [128][256] fp16
  _Float16* W2T = (_Float16*)(ws + o); o += 128 * 128 / 2;     // [128][128] fp16
  unsigned* deg       = (unsigned*)(ws + o); o += (size_t)N;
  unsigned* row_start = (unsigned*)(ws + o); o += (size_t)N;
  unsigned* bsum      = (unsigned*)(ws + o); o += 256;
  unsigned* boff      = (unsigned*)(ws + o); o += 256;
  unsigned* csr_src   = (unsigned*)(ws + o); o += (size_t)EE;
  unsigned* cntmat    = (unsigned*)(ws + o); o += (size_t)NB_CSR * N;  // 12.8 MB

  const int ngrid = (N + 3) / 4;
  const int ggrid = (N + 127) / 128;

  // ---- weight transpose+fp16 (tiny) ----
  convW_kernel<<<(256 * 128 + 255) / 256, 256, 0, stream>>>(W1, W1T, 256);
  convW_kernel<<<(128 * 128 + 255) / 256, 256, 0, stream>>>(W2, W2T, 128);

  // ---- CSR build (no global atomics; 2-D grid for full occupancy) ----
  count_kernel<<<dim3(NB_CSR, NCH), 256, 0, stream>>>(ei, E, N, cntmat);
  colscan_kernel<<<(N + 255) / 256, 256, 0, stream>>>(cntmat, deg, N);
  partial_sum_kernel<<<256, 256, 0, stream>>>(deg, bsum, N, C);
  scan_bsum_kernel<<<1, 256, 0, stream>>>(bsum, boff);
  rowstart_kernel<<<256, 256, 0, stream>>>(deg, boff, row_start, N, C);
  scatter2_kernel<<<dim3(NB_CSR, NCH), 256, 0, stream>>>(ei, E, N, cntmat, row_start, csr_src);

  // ---- layer 1 (K=256, H=4): A = x fp32 ----
  gemm_mfma_kernel<256, 4, true><<<ggrid, 256, 0, stream>>>(
      x, W1T, as1, ad1, h, asv, adv, N);
  aggregate_kernel<4, true><<<ngrid, 256, 0, stream>>>(
      row_start, deg, csr_src, (const __half*)h, asv, adv, b1, act1, N);

  // ---- layer 2 (K=128, H=1): A = act1 fp16 ----
  gemm_mfma_kernel<128, 1, false><<<ggrid, 256, 0, stream>>>(
      act1, W2T, as2, ad2, h, asv, adv, N);
  aggregate_kernel<1, false><<<ngrid, 256, 0, stream>>>(
      row_start, deg, csr_src, (const __half*)h, asv, adv, b2, out, N);
}

// Round 8
// 206.666 us; speedup vs baseline: 1.6117x; 1.1205x over previous
//
#include <hip/hip_runtime.h>
#include <hip/hip_fp16.h>

#define SLOPE_ATT 0.2f
#define SLOPE_ACT 0.01f

#define NB_CSR 128     // edge-range blocks in counting-sort passes
#define CHUNK 16384    // LDS histogram counters per chunk (64 KB)

typedef _Float16 hf8 __attribute__((ext_vector_type(8)));
typedef float f32x4 __attribute__((ext_vector_type(4)));

// ---------------------------------------------------------------------------
// MFMA fp16 GEMM body (device function): h[M][128] = A[M][K] @ B[K][128],
// BT[128][K] fp16. One wave = 32 rows x 128 cols. No LDS.
template<int K, int H, bool A_FP32>
__device__ __forceinline__
void gemm_mfma_body(int gbid, int tid,
                    const void* __restrict__ Av, const _Float16* __restrict__ BT,
                    const float* __restrict__ att_s, const float* __restrict__ att_d,
                    _Float16* __restrict__ hout, float* __restrict__ a_src,
                    float* __restrict__ a_dst, int M)
{
  const int lane = tid & 63;
  const int wid  = tid >> 6;
  const int li   = lane & 15;
  const int lk   = lane >> 4;
  const int rowbase = gbid * 128 + wid * 32;

  const float*    Af = (const float*)Av;
  const _Float16* Ah = (const _Float16*)Av;

  f32x4 acc[2][8];
#pragma unroll
  for (int i = 0; i < 2; ++i)
#pragma unroll
    for (int j = 0; j < 8; ++j) acc[i][j] = (f32x4){0.f, 0.f, 0.f, 0.f};

  const int r0 = min(rowbase + li,      M - 1);
  const int r1 = min(rowbase + 16 + li, M - 1);

#pragma unroll
  for (int ks = 0; ks < K / 32; ++ks) {
    const int kb = ks * 32 + lk * 8;
    hf8 a0, a1;
    if constexpr (A_FP32) {
      const float* p0 = &Af[(size_t)r0 * K + kb];
      const float* p1 = &Af[(size_t)r1 * K + kb];
      float4 x0a = *(const float4*)p0, x0b = *(const float4*)(p0 + 4);
      float4 x1a = *(const float4*)p1, x1b = *(const float4*)(p1 + 4);
      a0[0]=(_Float16)x0a.x; a0[1]=(_Float16)x0a.y; a0[2]=(_Float16)x0a.z; a0[3]=(_Float16)x0a.w;
      a0[4]=(_Float16)x0b.x; a0[5]=(_Float16)x0b.y; a0[6]=(_Float16)x0b.z; a0[7]=(_Float16)x0b.w;
      a1[0]=(_Float16)x1a.x; a1[1]=(_Float16)x1a.y; a1[2]=(_Float16)x1a.z; a1[3]=(_Float16)x1a.w;
      a1[4]=(_Float16)x1b.x; a1[5]=(_Float16)x1b.y; a1[6]=(_Float16)x1b.z; a1[7]=(_Float16)x1b.w;
    } else {
      a0 = *(const hf8*)&Ah[(size_t)r0 * K + kb];
      a1 = *(const hf8*)&Ah[(size_t)r1 * K + kb];
    }
#pragma unroll
    for (int cf = 0; cf < 8; ++cf) {
      hf8 b = *(const hf8*)&BT[(size_t)(cf * 16 + li) * K + kb];
      acc[0][cf] = __builtin_amdgcn_mfma_f32_16x16x32_f16(a0, b, acc[0][cf], 0, 0, 0);
      acc[1][cf] = __builtin_amdgcn_mfma_f32_16x16x32_f16(a1, b, acc[1][cf], 0, 0, 0);
    }
  }

  float sA[8], dA[8];
#pragma unroll
  for (int cf = 0; cf < 8; ++cf) {
    sA[cf] = att_s[cf * 16 + li];
    dA[cf] = att_d[cf * 16 + li];
  }

  const bool full = (rowbase + 32) <= M;
#pragma unroll
  for (int rf = 0; rf < 2; ++rf) {
    const int rb = rowbase + rf * 16 + lk * 4;
#pragma unroll
    for (int reg = 0; reg < 4; ++reg) {
      const int r = rb + reg;
      if (full || r < M) {
#pragma unroll
        for (int cf = 0; cf < 8; ++cf)
          hout[(size_t)r * 128 + cf * 16 + li] = (_Float16)acc[rf][cf][reg];
      }
    }
    if constexpr (H == 4) {
#pragma unroll
      for (int hh = 0; hh < 4; ++hh) {
#pragma unroll
        for (int reg = 0; reg < 4; ++reg) {
          float sp = acc[rf][2*hh][reg] * sA[2*hh] + acc[rf][2*hh+1][reg] * sA[2*hh+1];
          float dp = acc[rf][2*hh][reg] * dA[2*hh] + acc[rf][2*hh+1][reg] * dA[2*hh+1];
          sp += __shfl_xor(sp, 1); sp += __shfl_xor(sp, 2);
          sp += __shfl_xor(sp, 4); sp += __shfl_xor(sp, 8);
          dp += __shfl_xor(dp, 1); dp += __shfl_xor(dp, 2);
          dp += __shfl_xor(dp, 4); dp += __shfl_xor(dp, 8);
          const int r = rb + reg;
          if (li == 0 && r < M) {
            a_src[(size_t)r * 4 + hh] = sp;
            a_dst[(size_t)r * 4 + hh] = dp;
          }
        }
      }
    } else {
#pragma unroll
      for (int reg = 0; reg < 4; ++reg) {
        float sp = 0.f, dp = 0.f;
#pragma unroll
        for (int cf = 0; cf < 8; ++cf) {
          sp += acc[rf][cf][reg] * sA[cf];
          dp += acc[rf][cf][reg] * dA[cf];
        }
        sp += __shfl_xor(sp, 1); sp += __shfl_xor(sp, 2);
        sp += __shfl_xor(sp, 4); sp += __shfl_xor(sp, 8);
        dp += __shfl_xor(dp, 1); dp += __shfl_xor(dp, 2);
        dp += __shfl_xor(dp, 4); dp += __shfl_xor(dp, 8);
        const int r = rb + reg;
        if (li == 0 && r < M) { a_src[r] = sp; a_dst[r] = dp; }
      }
    }
  }
}

// standalone gemm for layer 2
template<int K, int H, bool A_FP32>
__global__ __launch_bounds__(256)
void gemm_mfma_kernel(const void* __restrict__ Av, const _Float16* __restrict__ BT,
                      const float* __restrict__ att_s, const float* __restrict__ att_d,
                      _Float16* __restrict__ hout, float* __restrict__ a_src,
                      float* __restrict__ a_dst, int M)
{
  gemm_mfma_body<K, H, A_FP32>(blockIdx.x, threadIdx.x, Av, BT, att_s, att_d,
                               hout, a_src, a_dst, M);
}

// ---------------------------------------------------------------------------
// FUSED: count (counting-sort pass 1) || convW1 || convW2.
// Grid: [0, NB*NCH) count; [NB*NCH, +128) W1; [+128, +64) W2.
__global__ __launch_bounds__(256)
void fused_pre_kernel(const int* __restrict__ ei, int E, int N,
                      unsigned* __restrict__ cntmat,
                      const float* __restrict__ W1, _Float16* __restrict__ W1T,
                      const float* __restrict__ W2, _Float16* __restrict__ W2T,
                      int ncount)
{
  __shared__ unsigned cnt[CHUNK];
  const int bid = blockIdx.x;
  if (bid < ncount) {
    const int b = bid % NB_CSR;
    const int c0 = (bid / NB_CSR) * CHUNK;
    const int clen = min(CHUNK, N - c0);
    const int EE = E + N;
    const int epb = (EE + NB_CSR - 1) / NB_CSR;
    const int lo = b * epb, hi = min(lo + epb, EE);

    for (int j = threadIdx.x; j < clen; j += 256) cnt[j] = 0;
    __syncthreads();
    for (int i = lo + threadIdx.x; i < hi; i += 256) {
      int d = (i < E) ? ei[E + i] : (i - E);
      int r = d - c0;
      if (r >= 0 && r < clen) atomicAdd(&cnt[r], 1u);
    }
    __syncthreads();
    for (int j = threadIdx.x; j < clen; j += 256)
      cntmat[(size_t)b * N + c0 + j] = cnt[j];
  } else {
    int rem = bid - ncount;
    if (rem < 128) {            // W1: 256x128 = 32768 elems
      int idx = rem * 256 + threadIdx.x;
      int k = idx >> 7, c = idx & 127;
      W1T[(size_t)c * 256 + k] = (_Float16)W1[idx];
    } else {                    // W2: 128x128 = 16384 elems
      int idx = (rem - 128) * 256 + threadIdx.x;
      int k = idx >> 7, c = idx & 127;
      W2T[(size_t)c * 128 + k] = (_Float16)W2[idx];
    }
  }
}

// colscan + per-block deg reduction -> bsum[blk]. Grid: ceil(N/256).
__global__ __launch_bounds__(256)
void colscan_kernel(unsigned* __restrict__ cntmat, unsigned* __restrict__ deg,
                    unsigned* __restrict__ bsum, int N)
{
  __shared__ unsigned red[256];
  const int d = blockIdx.x * 256 + threadIdx.x;
  unsigned off = 0;
  if (d < N) {
#pragma unroll 8
    for (int b = 0; b < NB_CSR; ++b) {
      unsigned t = cntmat[(size_t)b * N + d];
      cntmat[(size_t)b * N + d] = off;
      off += t;
    }
    deg[d] = off;
  }
  red[threadIdx.x] = off;
  __syncthreads();
  for (int o = 128; o; o >>= 1) {
    if (threadIdx.x < o) red[threadIdx.x] += red[threadIdx.x + o];
    __syncthreads();
  }
  if (threadIdx.x == 0) bsum[blockIdx.x] = red[0];
}

// Single-block scan of nblk block sums -> boff (exclusive). nblk <= 256.
__global__ __launch_bounds__(256)
void scan_bsum_kernel(const unsigned* __restrict__ bsum, unsigned* __restrict__ boff,
                      int nblk)
{
  __shared__ unsigned s[256];
  const int t = threadIdx.x;
  unsigned v0 = (t < nblk) ? bsum[t] : 0u;
  s[t] = v0;
  __syncthreads();
  for (int off = 1; off < 256; off <<= 1) {
    unsigned v = (t >= off) ? s[t - off] : 0u;
    __syncthreads();
    s[t] += v;
    __syncthreads();
  }
  if (t < nblk) boff[t] = s[t] - v0;
}

// Grid: ceil(N/256); per-block scan of 256 deg + boff -> row_start.
__global__ __launch_bounds__(256)
void rowstart_kernel(const unsigned* __restrict__ deg, const unsigned* __restrict__ boff,
                     unsigned* __restrict__ row_start, int N)
{
  __shared__ unsigned s[256];
  const int t = threadIdx.x;
  const int i = blockIdx.x * 256 + t;
  const unsigned d = (i < N) ? deg[i] : 0u;
  s[t] = d;
  __syncthreads();
  for (int off = 1; off < 256; off <<= 1) {
    unsigned v = (t >= off) ? s[t - off] : 0u;
    __syncthreads();
    s[t] += v;
    __syncthreads();
  }
  if (i < N) row_start[i] = boff[blockIdx.x] + s[t] - d;
}

// FUSED: scatter2 (counting-sort pass 3) || gemm layer-1.
// Grid: [0, NB*NCH) scatter; [NB*NCH, +ggrid) gemm1.
__global__ __launch_bounds__(256)
void fused_mid_kernel(const int* __restrict__ ei, int E, int N,
                      const unsigned* __restrict__ cntmat,
                      const unsigned* __restrict__ row_start,
                      unsigned* __restrict__ csr_src,
                      const float* __restrict__ x, const _Float16* __restrict__ W1T,
                      const float* __restrict__ as1, const float* __restrict__ ad1,
                      _Float16* __restrict__ h, float* __restrict__ asv,
                      float* __restrict__ adv, int nscatter)
{
  __shared__ unsigned cnt[CHUNK];
  const int bid = blockIdx.x;
  if (bid < nscatter) {
    const int b = bid % NB_CSR;
    const int c0 = (bid / NB_CSR) * CHUNK;
    const int clen = min(CHUNK, N - c0);
    const int EE = E + N;
    const int epb = (EE + NB_CSR - 1) / NB_CSR;
    const int lo = b * epb, hi = min(lo + epb, EE);

    for (int j = threadIdx.x; j < clen; j += 256) cnt[j] = 0;
    __syncthreads();
    for (int i = lo + threadIdx.x; i < hi; i += 256) {
      int s, d;
      if (i < E) { s = ei[i]; d = ei[E + i]; } else { s = d = i - E; }
      int r = d - c0;
      if (r >= 0 && r < clen) {
        unsigned rank = atomicAdd(&cnt[r], 1u);
        unsigned pos = row_start[d] + cntmat[(size_t)b * N + d] + rank;
        csr_src[pos] = (unsigned)s;
      }
    }
  } else {
    gemm_mfma_body<256, 4, true>(bid - nscatter, threadIdx.x, x, W1T, as1, ad1,
                                 h, asv, adv, N);
  }
}

// ---------------------------------------------------------------------------
// Fused per-node aggregation (unchanged from R7).
template<int H, bool OUT_HALF>
__global__ __launch_bounds__(256)
void aggregate_kernel(const unsigned* __restrict__ row_start,
                      const unsigned* __restrict__ deg,
                      const unsigned* __restrict__ csr_src,
                      const __half* __restrict__ h,
                      const float* __restrict__ a_src,
                      const float* __restrict__ a_dst,
                      const float* __restrict__ bias,
                      void* __restrict__ outv, int N)
{
  const int n = blockIdx.x * 4 + (threadIdx.x >> 6);
  if (n >= N) return;
  const int l = threadIdx.x & 63;
  const int hd = (H == 4) ? (l >> 4) : 0;

  const float adn = a_dst[(size_t)n * H + hd];
  const unsigned beg = row_start[n];
  const unsigned cnt = deg[n];              // >= 1 (self loop)
  const __half2* __restrict__ h2 = (const __half2*)h;

  float Z = 0.f, ax = 0.f, ay = 0.f;
  unsigned i = 0;
  for (; i + 4 <= cnt; i += 4) {
    unsigned s0 = csr_src[beg + i];
    unsigned s1 = csr_src[beg + i + 1];
    unsigned s2 = csr_src[beg + i + 2];
    unsigned s3 = csr_src[beg + i + 3];
    float e0 = a_src[(size_t)s0 * H + hd] + adn;
    float e1 = a_src[(size_t)s1 * H + hd] + adn;
    float e2 = a_src[(size_t)s2 * H + hd] + adn;
    float e3 = a_src[(size_t)s3 * H + hd] + adn;
    float2 v0 = __half22float2(h2[(size_t)s0 * 64 + l]);
    float2 v1 = __half22float2(h2[(size_t)s1 * 64 + l]);
    float2 v2 = __half22float2(h2[(size_t)s2 * 64 + l]);
    float2 v3 = __half22float2(h2[(size_t)s3 * 64 + l]);
    e0 = (e0 >= 0.f) ? e0 : SLOPE_ATT * e0;
    e1 = (e1 >= 0.f) ? e1 : SLOPE_ATT * e1;
    e2 = (e2 >= 0.f) ? e2 : SLOPE_ATT * e2;
    e3 = (e3 >= 0.f) ? e3 : SLOPE_ATT * e3;
    float w0 = __expf(e0), w1 = __expf(e1), w2 = __expf(e2), w3 = __expf(e3);
    Z  += (w0 + w1) + (w2 + w3);
    ax += w0 * v0.x + w1 * v1.x + w2 * v2.x + w3 * v3.x;
    ay += w0 * v0.y + w1 * v1.y + w2 * v2.y + w3 * v3.y;
  }
  for (; i < cnt; ++i) {
    unsigned s0 = csr_src[beg + i];
    float e0 = a_src[(size_t)s0 * H + hd] + adn;
    e0 = (e0 >= 0.f) ? e0 : SLOPE_ATT * e0;
    float w0 = __expf(e0);
    float2 v0 = __half22float2(h2[(size_t)s0 * 64 + l]);
    Z  += w0;
    ax += w0 * v0.x;
    ay += w0 * v0.y;
  }
  const float inv = 1.f / (Z + 1e-16f);
  float2 b = ((const float2*)bias)[l];
  float ox = ax * inv + b.x;
  float oy = ay * inv + b.y;
  ox = (ox >= 0.f) ? ox : SLOPE_ACT * ox;
  oy = (oy >= 0.f) ? oy : SLOPE_ACT * oy;
  if constexpr (OUT_HALF)
    ((__half2*)outv)[(size_t)n * 64 + l] = __floats2half2_rn(ox, oy);
  else
    ((float2*)outv)[(size_t)n * 64 + l] = make_float2(ox, oy);
}

// ---------------------------------------------------------------------------
extern "C" void kernel_launch(void* const* d_in, const int* in_sizes, int n_in,
                              void* d_out, int out_size, void* d_ws, size_t ws_size,
                              hipStream_t stream)
{
  const float* x   = (const float*)d_in[0];
  const int*   ei  = (const int*)d_in[1];
  const float* W1  = (const float*)d_in[2];
  const float* as1 = (const float*)d_in[3];
  const float* ad1 = (const float*)d_in[4];
  const float* b1  = (const float*)d_in[5];
  const float* W2  = (const float*)d_in[6];
  const float* as2 = (const float*)d_in[7];
  const float* ad2 = (const float*)d_in[8];
  const float* b2  = (const float*)d_in[9];
  float* out = (float*)d_out;

  const int N  = in_sizes[0] / 256;
  const int E  = in_sizes[1] / 2;
  const int EE = E + N;
  const int NCH  = (N + CHUNK - 1) / CHUNK;   // dst chunks
  const int nblk = (N + 255) / 256;           // <= 256 for N <= 65536
  const int NSC  = NB_CSR * NCH;              // counting-sort blocks

  float* ws = (float*)d_ws;
  size_t o = 0;
  _Float16* h    = (_Float16*)(ws + o); o += (size_t)N * 64;   // [N][128] fp16
  _Float16* act1 = (_Float16*)(ws + o); o += (size_t)N * 64;   // [N][128] fp16
  float* asv = ws + o; o += (size_t)N * 4;
  float* adv = ws + o; o += (size_t)N * 4;
  _Float16* W1T = (_Float16*)(ws + o); o += 128 * 256 / 2;     // [128][256] fp16
  _Float16* W2T = (_Float16*)(ws + o); o += 128 * 128 / 2;     // [128][128] fp16
  unsigned* deg       = (unsigned*)(ws + o); o += (size_t)N;
  unsigned* row_start = (unsigned*)(ws + o); o += (size_t)N;
  unsigned* bsum      = (unsigned*)(ws + o); o += 256;
  unsigned* boff      = (unsigned*)(ws + o); o += 256;
  unsigned* csr_src   = (unsigned*)(ws + o); o += (size_t)EE;
  unsigned* cntmat    = (unsigned*)(ws + o); o += (size_t)NB_CSR * N;  // 25.6 MB

  const int ngrid = (N + 3) / 4;
  const int ggrid = (N + 127) / 128;

  // 1) count || convW1 || convW2
  fused_pre_kernel<<<NSC + 128 + 64, 256, 0, stream>>>(
      ei, E, N, cntmat, W1, W1T, W2, W2T, NSC);
  // 2) column scan + block sums
  colscan_kernel<<<nblk, 256, 0, stream>>>(cntmat, deg, bsum, N);
  // 3) scan block sums
  scan_bsum_kernel<<<1, 256, 0, stream>>>(bsum, boff, nblk);
  // 4) row starts
  rowstart_kernel<<<nblk, 256, 0, stream>>>(deg, boff, row_start, N);
  // 5) scatter || gemm layer-1
  fused_mid_kernel<<<NSC + ggrid, 256, 0, stream>>>(
      ei, E, N, cntmat, row_start, csr_src, x, W1T, as1, ad1, h, asv, adv, NSC);
  // 6) aggregate layer-1 -> act1 (fp16)
  aggregate_kernel<4, true><<<ngrid, 256, 0, stream>>>(
      row_start, deg, csr_src, (const __half*)h, asv, adv, b1, act1, N);
  // 7) gemm layer-2
  gemm_mfma_kernel<128, 1, false><<<ggrid, 256, 0, stream>>>(
      act1, W2T, as2, ad2, h, asv, adv, N);
  // 8) aggregate layer-2 -> out (fp32)
  aggregate_kernel<1, false><<<ngrid, 256, 0, stream>>>(
      row_start, deg, csr_src, (const __half*)h, asv, adv, b2, out, N);
}

// Round 9
// 195.070 us; speedup vs baseline: 1.7075x; 1.0594x over previous
//
#include <hip/hip_runtime.h>
#include <hip/hip_fp16.h>

#define SLOPE_ATT 0.2f
#define SLOPE_ACT 0.01f

#define NB_CSR 128     // edge-range blocks in counting-sort passes
#define CHUNK 8192     // LDS histogram counters per chunk (32 KB -> 5 blk/CU)

typedef _Float16 hf8 __attribute__((ext_vector_type(8)));
typedef float f32x4 __attribute__((ext_vector_type(4)));

// ---------------------------------------------------------------------------
// MFMA fp16 GEMM body: h[M][128] = A[M][K] @ B[K][128], BT[128][K] fp16.
// One wave = 32 rows x 128 cols. No LDS.
template<int K, int H, bool A_FP32>
__device__ __forceinline__
void gemm_mfma_body(int gbid, int tid,
                    const void* __restrict__ Av, const _Float16* __restrict__ BT,
                    const float* __restrict__ att_s, const float* __restrict__ att_d,
                    _Float16* __restrict__ hout, float* __restrict__ a_src,
                    float* __restrict__ a_dst, int M)
{
  const int lane = tid & 63;
  const int wid  = tid >> 6;
  const int li   = lane & 15;
  const int lk   = lane >> 4;
  const int rowbase = gbid * 128 + wid * 32;

  const float*    Af = (const float*)Av;
  const _Float16* Ah = (const _Float16*)Av;

  f32x4 acc[2][8];
#pragma unroll
  for (int i = 0; i < 2; ++i)
#pragma unroll
    for (int j = 0; j < 8; ++j) acc[i][j] = (f32x4){0.f, 0.f, 0.f, 0.f};

  const int r0 = min(rowbase + li,      M - 1);
  const int r1 = min(rowbase + 16 + li, M - 1);

#pragma unroll
  for (int ks = 0; ks < K / 32; ++ks) {
    const int kb = ks * 32 + lk * 8;
    hf8 a0, a1;
    if constexpr (A_FP32) {
      const float* p0 = &Af[(size_t)r0 * K + kb];
      const float* p1 = &Af[(size_t)r1 * K + kb];
      float4 x0a = *(const float4*)p0, x0b = *(const float4*)(p0 + 4);
      float4 x1a = *(const float4*)p1, x1b = *(const float4*)(p1 + 4);
      a0[0]=(_Float16)x0a.x; a0[1]=(_Float16)x0a.y; a0[2]=(_Float16)x0a.z; a0[3]=(_Float16)x0a.w;
      a0[4]=(_Float16)x0b.x; a0[5]=(_Float16)x0b.y; a0[6]=(_Float16)x0b.z; a0[7]=(_Float16)x0b.w;
      a1[0]=(_Float16)x1a.x; a1[1]=(_Float16)x1a.y; a1[2]=(_Float16)x1a.z; a1[3]=(_Float16)x1a.w;
      a1[4]=(_Float16)x1b.x; a1[5]=(_Float16)x1b.y; a1[6]=(_Float16)x1b.z; a1[7]=(_Float16)x1b.w;
    } else {
      a0 = *(const hf8*)&Ah[(size_t)r0 * K + kb];
      a1 = *(const hf8*)&Ah[(size_t)r1 * K + kb];
    }
#pragma unroll
    for (int cf = 0; cf < 8; ++cf) {
      hf8 b = *(const hf8*)&BT[(size_t)(cf * 16 + li) * K + kb];
      acc[0][cf] = __builtin_amdgcn_mfma_f32_16x16x32_f16(a0, b, acc[0][cf], 0, 0, 0);
      acc[1][cf] = __builtin_amdgcn_mfma_f32_16x16x32_f16(a1, b, acc[1][cf], 0, 0, 0);
    }
  }

  float sA[8], dA[8];
#pragma unroll
  for (int cf = 0; cf < 8; ++cf) {
    sA[cf] = att_s[cf * 16 + li];
    dA[cf] = att_d[cf * 16 + li];
  }

  const bool full = (rowbase + 32) <= M;
#pragma unroll
  for (int rf = 0; rf < 2; ++rf) {
    const int rb = rowbase + rf * 16 + lk * 4;
#pragma unroll
    for (int reg = 0; reg < 4; ++reg) {
      const int r = rb + reg;
      if (full || r < M) {
#pragma unroll
        for (int cf = 0; cf < 8; ++cf)
          hout[(size_t)r * 128 + cf * 16 + li] = (_Float16)acc[rf][cf][reg];
      }
    }
    if constexpr (H == 4) {
#pragma unroll
      for (int hh = 0; hh < 4; ++hh) {
#pragma unroll
        for (int reg = 0; reg < 4; ++reg) {
          float sp = acc[rf][2*hh][reg] * sA[2*hh] + acc[rf][2*hh+1][reg] * sA[2*hh+1];
          float dp = acc[rf][2*hh][reg] * dA[2*hh] + acc[rf][2*hh+1][reg] * dA[2*hh+1];
          sp += __shfl_xor(sp, 1); sp += __shfl_xor(sp, 2);
          sp += __shfl_xor(sp, 4); sp += __shfl_xor(sp, 8);
          dp += __shfl_xor(dp, 1); dp += __shfl_xor(dp, 2);
          dp += __shfl_xor(dp, 4); dp += __shfl_xor(dp, 8);
          const int r = rb + reg;
          if (li == 0 && r < M) {
            a_src[(size_t)r * 4 + hh] = sp;
            a_dst[(size_t)r * 4 + hh] = dp;
          }
        }
      }
    } else {
#pragma unroll
      for (int reg = 0; reg < 4; ++reg) {
        float sp = 0.f, dp = 0.f;
#pragma unroll
        for (int cf = 0; cf < 8; ++cf) {
          sp += acc[rf][cf][reg] * sA[cf];
          dp += acc[rf][cf][reg] * dA[cf];
        }
        sp += __shfl_xor(sp, 1); sp += __shfl_xor(sp, 2);
        sp += __shfl_xor(sp, 4); sp += __shfl_xor(sp, 8);
        dp += __shfl_xor(dp, 1); dp += __shfl_xor(dp, 2);
        dp += __shfl_xor(dp, 4); dp += __shfl_xor(dp, 8);
        const int r = rb + reg;
        if (li == 0 && r < M) { a_src[r] = sp; a_dst[r] = dp; }
      }
    }
  }
}

template<int K, int H, bool A_FP32>
__global__ __launch_bounds__(256)
void gemm_mfma_kernel(const void* __restrict__ Av, const _Float16* __restrict__ BT,
                      const float* __restrict__ att_s, const float* __restrict__ att_d,
                      _Float16* __restrict__ hout, float* __restrict__ a_src,
                      float* __restrict__ a_dst, int M)
{
  gemm_mfma_body<K, H, A_FP32>(blockIdx.x, threadIdx.x, Av, BT, att_s, att_d,
                               hout, a_src, a_dst, M);
}

// ---------------------------------------------------------------------------
// FUSED: count (LDS histogram, records per-edge rank) || convW1 || convW2.
// Grid: [0, NSC) count; then 128 blocks W1; then 64 blocks W2.
__global__ __launch_bounds__(256)
void fused_pre_kernel(const int* __restrict__ ei, int E, int N,
                      unsigned short* __restrict__ cnt16mat,
                      unsigned short* __restrict__ rank16,
                      const float* __restrict__ W1, _Float16* __restrict__ W1T,
                      const float* __restrict__ W2, _Float16* __restrict__ W2T,
                      int ncount)
{
  __shared__ unsigned cnt[CHUNK];
  const int bid = blockIdx.x;
  if (bid < ncount) {
    const int b = bid % NB_CSR;
    const int c0 = (bid / NB_CSR) * CHUNK;
    const int clen = min(CHUNK, N - c0);
    const int EE = E + N;
    const int epb = (EE + NB_CSR - 1) / NB_CSR;
    const int lo = b * epb, hi = min(lo + epb, EE);

    for (int j = threadIdx.x; j < clen; j += 256) cnt[j] = 0;
    __syncthreads();
    for (int i = lo + threadIdx.x; i < hi; i += 256) {
      int d = (i < E) ? ei[E + i] : (i - E);
      int r = d - c0;
      if (r >= 0 && r < clen) {
        unsigned rank = atomicAdd(&cnt[r], 1u);
        rank16[i] = (unsigned short)rank;
      }
    }
    __syncthreads();
    for (int j = threadIdx.x; j < clen; j += 256)
      cnt16mat[(size_t)b * N + c0 + j] = (unsigned short)cnt[j];
  } else {
    int rem = bid - ncount;
    if (rem < 128) {            // W1: 256x128 = 32768 elems
      int idx = rem * 256 + threadIdx.x;
      int k = idx >> 7, c = idx & 127;
      W1T[(size_t)c * 256 + k] = (_Float16)W1[idx];
    } else {                    // W2: 128x128 = 16384 elems
      int idx = (rem - 128) * 256 + threadIdx.x;
      int k = idx >> 7, c = idx & 127;
      W2T[(size_t)c * 128 + k] = (_Float16)W2[idx];
    }
  }
}

// Column scan over blocks per dst (u16, 2 dsts/thread packed) -> deg, bsum.
// Grid: ceil(N/512) blocks of 256 (each thread owns 2 adjacent dsts). N even.
__global__ __launch_bounds__(256)
void colscan_kernel(unsigned short* __restrict__ cnt16mat,
                    unsigned* __restrict__ deg, unsigned* __restrict__ bsum, int N)
{
  __shared__ unsigned red[256];
  const int d2 = blockIdx.x * 256 + threadIdx.x;   // pair index
  const int N2 = N >> 1;
  unsigned off0 = 0, off1 = 0;
  if (d2 < N2) {
    unsigned* pm = (unsigned*)cnt16mat;
#pragma unroll 8
    for (int b = 0; b < NB_CSR; ++b) {
      unsigned t = pm[(size_t)b * N2 + d2];
      pm[(size_t)b * N2 + d2] = off0 | (off1 << 16);
      off0 += t & 0xFFFFu;
      off1 += t >> 16;
    }
    deg[2 * d2]     = off0;
    deg[2 * d2 + 1] = off1;
  }
  red[threadIdx.x] = off0 + off1;
  __syncthreads();
  for (int o = 128; o; o >>= 1) {
    if (threadIdx.x < o) red[threadIdx.x] += red[threadIdx.x + o];
    __syncthreads();
  }
  if (threadIdx.x == 0) bsum[blockIdx.x] = red[0];
}

// Single-block exclusive scan of nblk block sums (nblk <= 256).
__global__ __launch_bounds__(256)
void scan_bsum_kernel(const unsigned* __restrict__ bsum, unsigned* __restrict__ boff,
                      int nblk)
{
  __shared__ unsigned s[256];
  const int t = threadIdx.x;
  unsigned v0 = (t < nblk) ? bsum[t] : 0u;
  s[t] = v0;
  __syncthreads();
  for (int off = 1; off < 256; off <<= 1) {
    unsigned v = (t >= off) ? s[t - off] : 0u;
    __syncthreads();
    s[t] += v;
    __syncthreads();
  }
  if (t < nblk) boff[t] = s[t] - v0;
}

// row_start: per-block scan of 512 deg (2/thread) + boff. Grid: ceil(N/512).
__global__ __launch_bounds__(256)
void rowstart_kernel(const unsigned* __restrict__ deg, const unsigned* __restrict__ boff,
                     unsigned* __restrict__ row_start, int N)
{
  __shared__ unsigned s[256];
  const int t = threadIdx.x;
  const int i = blockIdx.x * 512 + t * 2;
  unsigned d0 = (i < N) ? deg[i] : 0u;
  unsigned d1 = (i + 1 < N) ? deg[i + 1] : 0u;
  s[t] = d0 + d1;
  __syncthreads();
  for (int off = 1; off < 256; off <<= 1) {
    unsigned v = (t >= off) ? s[t - off] : 0u;
    __syncthreads();
    s[t] += v;
    __syncthreads();
  }
  unsigned base = boff[blockIdx.x] + s[t] - (d0 + d1);
  if (i < N)     row_start[i] = base;
  if (i + 1 < N) row_start[i + 1] = base + d0;
}

// FUSED (both paths LDS-free): gemm layer-1 || edge-parallel scatter.
// Grid: [0, ggrid) gemm1; [ggrid, ggrid+sgrid) scatter.
__global__ __launch_bounds__(256)
void fused_mid_kernel(const int* __restrict__ ei, int E, int N, int epb,
                      const unsigned short* __restrict__ cnt16mat,
                      const unsigned short* __restrict__ rank16,
                      const unsigned* __restrict__ row_start,
                      unsigned* __restrict__ csr_src,
                      const float* __restrict__ x, const _Float16* __restrict__ W1T,
                      const float* __restrict__ as1, const float* __restrict__ ad1,
                      _Float16* __restrict__ h, float* __restrict__ asv,
                      float* __restrict__ adv, int ggrid)
{
  const int bid = blockIdx.x;
  if (bid < ggrid) {
    gemm_mfma_body<256, 4, true>(bid, threadIdx.x, x, W1T, as1, ad1,
                                 h, asv, adv, N);
  } else {
    const int i = (bid - ggrid) * 256 + threadIdx.x;
    const int EE = E + N;
    if (i < EE) {
      int s, d;
      if (i < E) { s = ei[i]; d = ei[E + i]; } else { s = d = i - E; }
      const int b = i / epb;
      unsigned pos = row_start[d] + cnt16mat[(size_t)b * N + d] + rank16[i];
      csr_src[pos] = (unsigned)s;
    }
  }
}

// ---------------------------------------------------------------------------
// Fused per-node aggregation (unchanged).
template<int H, bool OUT_HALF>
__global__ __launch_bounds__(256)
void aggregate_kernel(const unsigned* __restrict__ row_start,
                      const unsigned* __restrict__ deg,
                      const unsigned* __restrict__ csr_src,
                      const __half* __restrict__ h,
                      const float* __restrict__ a_src,
                      const float* __restrict__ a_dst,
                      const float* __restrict__ bias,
                      void* __restrict__ outv, int N)
{
  const int n = blockIdx.x * 4 + (threadIdx.x >> 6);
  if (n >= N) return;
  const int l = threadIdx.x & 63;
  const int hd = (H == 4) ? (l >> 4) : 0;

  const float adn = a_dst[(size_t)n * H + hd];
  const unsigned beg = row_start[n];
  const unsigned cnt = deg[n];              // >= 1 (self loop)
  const __half2* __restrict__ h2 = (const __half2*)h;

  float Z = 0.f, ax = 0.f, ay = 0.f;
  unsigned i = 0;
  for (; i + 4 <= cnt; i += 4) {
    unsigned s0 = csr_src[beg + i];
    unsigned s1 = csr_src[beg + i + 1];
    unsigned s2 = csr_src[beg + i + 2];
    unsigned s3 = csr_src[beg + i + 3];
    float e0 = a_src[(size_t)s0 * H + hd] + adn;
    float e1 = a_src[(size_t)s1 * H + hd] + adn;
    float e2 = a_src[(size_t)s2 * H + hd] + adn;
    float e3 = a_src[(size_t)s3 * H + hd] + adn;
    float2 v0 = __half22float2(h2[(size_t)s0 * 64 + l]);
    float2 v1 = __half22float2(h2[(size_t)s1 * 64 + l]);
    float2 v2 = __half22float2(h2[(size_t)s2 * 64 + l]);
    float2 v3 = __half22float2(h2[(size_t)s3 * 64 + l]);
    e0 = (e0 >= 0.f) ? e0 : SLOPE_ATT * e0;
    e1 = (e1 >= 0.f) ? e1 : SLOPE_ATT * e1;
    e2 = (e2 >= 0.f) ? e2 : SLOPE_ATT * e2;
    e3 = (e3 >= 0.f) ? e3 : SLOPE_ATT * e3;
    float w0 = __expf(e0), w1 = __expf(e1), w2 = __expf(e2), w3 = __expf(e3);
    Z  += (w0 + w1) + (w2 + w3);
    ax += w0 * v0.x + w1 * v1.x + w2 * v2.x + w3 * v3.x;
    ay += w0 * v0.y + w1 * v1.y + w2 * v2.y + w3 * v3.y;
  }
  for (; i < cnt; ++i) {
    unsigned s0 = csr_src[beg + i];
    float e0 = a_src[(size_t)s0 * H + hd] + adn;
    e0 = (e0 >= 0.f) ? e0 : SLOPE_ATT * e0;
    float w0 = __expf(e0);
    float2 v0 = __half22float2(h2[(size_t)s0 * 64 + l]);
    Z  += w0;
    ax += w0 * v0.x;
    ay += w0 * v0.y;
  }
  const float inv = 1.f / (Z + 1e-16f);
  float2 b = ((const float2*)bias)[l];
  float ox = ax * inv + b.x;
  float oy = ay * inv + b.y;
  ox = (ox >= 0.f) ? ox : SLOPE_ACT * ox;
  oy = (oy >= 0.f) ? oy : SLOPE_ACT * oy;
  if constexpr (OUT_HALF)
    ((__half2*)outv)[(size_t)n * 64 + l] = __floats2half2_rn(ox, oy);
  else
    ((float2*)outv)[(size_t)n * 64 + l] = make_float2(ox, oy);
}

// ---------------------------------------------------------------------------
extern "C" void kernel_launch(void* const* d_in, const int* in_sizes, int n_in,
                              void* d_out, int out_size, void* d_ws, size_t ws_size,
                              hipStream_t stream)
{
  const float* x   = (const float*)d_in[0];
  const int*   ei  = (const int*)d_in[1];
  const float* W1  = (const float*)d_in[2];
  const float* as1 = (const float*)d_in[3];
  const float* ad1 = (const float*)d_in[4];
  const float* b1  = (const float*)d_in[5];
  const float* W2  = (const float*)d_in[6];
  const float* as2 = (const float*)d_in[7];
  const float* ad2 = (const float*)d_in[8];
  const float* b2  = (const float*)d_in[9];
  float* out = (float*)d_out;

  const int N  = in_sizes[0] / 256;
  const int E  = in_sizes[1] / 2;
  const int EE = E + N;
  const int NCH  = (N + CHUNK - 1) / CHUNK;    // dst chunks
  const int nblk = (N + 511) / 512;            // colscan/rowstart blocks (<=256)
  const int NSC  = NB_CSR * NCH;               // count blocks
  const int epb  = (EE + NB_CSR - 1) / NB_CSR; // edges per count range

  float* ws = (float*)d_ws;
  size_t o = 0;
  _Float16* h    = (_Float16*)(ws + o); o += (size_t)N * 64;   // [N][128] fp16
  _Float16* act1 = (_Float16*)(ws + o); o += (size_t)N * 64;   // [N][128] fp16
  float* asv = ws + o; o += (size_t)N * 4;
  float* adv = ws + o; o += (size_t)N * 4;
  _Float16* W1T = (_Float16*)(ws + o); o += 128 * 256 / 2;     // [128][256] fp16
  _Float16* W2T = (_Float16*)(ws + o); o += 128 * 128 / 2;     // [128][128] fp16
  unsigned* deg       = (unsigned*)(ws + o); o += (size_t)N;
  unsigned* row_start = (unsigned*)(ws + o); o += (size_t)N;
  unsigned* bsum      = (unsigned*)(ws + o); o += 256;
  unsigned* boff      = (unsigned*)(ws + o); o += 256;
  unsigned* csr_src   = (unsigned*)(ws + o); o += (size_t)EE;
  unsigned short* cnt16mat = (unsigned short*)(ws + o); o += (size_t)NB_CSR * N / 2; // 12.8 MB
  unsigned short* rank16   = (unsigned short*)(ws + o); o += (size_t)(EE + 1) / 2;   // 1.7 MB

  const int ngrid = (N + 3) / 4;
  const int ggrid = (N + 127) / 128;
  const int sgrid = (EE + 255) / 256;

  // 1) count+rank || convW1 || convW2
  fused_pre_kernel<<<NSC + 128 + 64, 256, 0, stream>>>(
      ei, E, N, cnt16mat, rank16, W1, W1T, W2, W2T, NSC);
  // 2) column scan (packed u16 x2) + block sums
  colscan_kernel<<<nblk, 256, 0, stream>>>(cnt16mat, deg, bsum, N);
  // 3) scan block sums
  scan_bsum_kernel<<<1, 256, 0, stream>>>(bsum, boff, nblk);
  // 4) row starts
  rowstart_kernel<<<nblk, 256, 0, stream>>>(deg, boff, row_start, N);
  // 5) gemm layer-1 || edge-parallel scatter (both LDS-free)
  fused_mid_kernel<<<ggrid + sgrid, 256, 0, stream>>>(
      ei, E, N, epb, cnt16mat, rank16, row_start, csr_src,
      x, W1T, as1, ad1, h, asv, adv, ggrid);
  // 6) aggregate layer-1 -> act1 (fp16)
  aggregate_kernel<4, true><<<ngrid, 256, 0, stream>>>(
      row_start, deg, csr_src, (const __half*)h, asv, adv, b1, act1, N);
  // 7) gemm layer-2
  gemm_mfma_kernel<128, 1, false><<<ggrid, 256, 0, stream>>>(
      act1, W2T, as2, ad2, h, asv, adv, N);
  // 8) aggregate layer-2 -> out (fp32)
  aggregate_kernel<1, false><<<ngrid, 256, 0, stream>>>(
      row_start, deg, csr_src, (const __half*)h, asv, adv, b2, out, N);
}